// Round 5
// baseline (6370.182 us; speedup 1.0000x reference)
//
#include <hip/hip_runtime.h>
#include <hip/hip_cooperative_groups.h>

namespace cg = cooperative_groups;

// Problem constants
#define BSZ   128
#define NTOK  512
#define SDIM  256
#define PDIM  128
#define FDIM  256
#define NIT   30

typedef _Float16 half_t;
typedef _Float16 half8_t __attribute__((ext_vector_type(8)));

// =====================================================================
// K0: transpose W [256,128] -> Wt [128,256]
// =====================================================================
__global__ __launch_bounds__(256) void transpose_w_kernel(const float* __restrict__ W,
                                                          float* __restrict__ Wt) {
    int idx = blockIdx.x * 256 + threadIdx.x;   // [0, 32768)
    int d = idx >> 7;        // 0..255
    int p = idx & 127;       // 0..127
    Wt[p * 256 + d] = W[idx];
}

// =====================================================================
// K1: h = X@W + b -> LayerNorm -> *g+beta -> l2norm.
// =====================================================================
__global__ __launch_bounds__(256) void proj_kernel(const float* __restrict__ X,
                                                   const float* __restrict__ Wt,
                                                   const float* __restrict__ bias,
                                                   const float* __restrict__ gamma,
                                                   const float* __restrict__ beta,
                                                   float* __restrict__ out) {
    __shared__ float sX[32 * 66];
    __shared__ float sB[128 * 66];
    const int t = threadIdx.x;
    const int row0 = blockIdx.x * 32;
    const int cg = t & 31;      // col group
    const int rg = t >> 5;      // 0..7
    float acc[4][4] = {};

    for (int dc = 0; dc < 4; ++dc) {   // 4 k-chunks of 64
#pragma unroll
        for (int i = 0; i < 2; ++i) {  // stage 32x64 X chunk
            int e = t + 256 * i;
            int r = e >> 4, k4 = (e & 15) * 4;
            float4 v = *(const float4*)&X[(size_t)(row0 + r) * 256 + dc * 64 + k4];
            float* dst = &sX[r * 66 + k4];
            dst[0] = v.x; dst[1] = v.y; dst[2] = v.z; dst[3] = v.w;
        }
#pragma unroll
        for (int i = 0; i < 8; ++i) {  // stage 128x64 W chunk
            int e = t + 256 * i;
            int c = e >> 4, k4 = (e & 15) * 4;
            float4 v = *(const float4*)&Wt[(size_t)c * 256 + dc * 64 + k4];
            float* dst = &sB[c * 66 + k4];
            dst[0] = v.x; dst[1] = v.y; dst[2] = v.z; dst[3] = v.w;
        }
        __syncthreads();
#pragma unroll 8
        for (int kk = 0; kk < 64; kk += 2) {
            float2 a2[4], b2[4];
#pragma unroll
            for (int j = 0; j < 4; ++j) b2[j] = *(const float2*)&sB[(cg + 32 * j) * 66 + kk];
#pragma unroll
            for (int i = 0; i < 4; ++i) a2[i] = *(const float2*)&sX[(rg + 8 * i) * 66 + kk];
#pragma unroll
            for (int i = 0; i < 4; ++i)
#pragma unroll
                for (int j = 0; j < 4; ++j)
                    acc[i][j] += a2[i].x * b2[j].x + a2[i].y * b2[j].y;
        }
        __syncthreads();
    }

    float bia[4], gam[4], bet[4];
#pragma unroll
    for (int j = 0; j < 4; ++j) {
        int c = cg + 32 * j;
        bia[j] = bias[c]; gam[j] = gamma[c]; bet[j] = beta[c];
    }

#pragma unroll
    for (int i = 0; i < 4; ++i) {
        int r = rg + 8 * i;
        float h[4];
        float s1 = 0.f, s2 = 0.f;
#pragma unroll
        for (int j = 0; j < 4; ++j) {
            h[j] = acc[i][j] + bia[j];
            s1 += h[j];
            s2 += h[j] * h[j];
        }
        for (int m = 1; m < 32; m <<= 1) {
            s1 += __shfl_xor(s1, m);
            s2 += __shfl_xor(s2, m);
        }
        float mu  = s1 * (1.f / 128.f);
        float var = s2 * (1.f / 128.f) - mu * mu;
        float rstd = 1.f / sqrtf(var + 1e-5f);
        float y[4]; float s3 = 0.f;
#pragma unroll
        for (int j = 0; j < 4; ++j) {
            y[j] = (h[j] - mu) * rstd * gam[j] + bet[j];
            s3 += y[j] * y[j];
        }
        for (int m = 1; m < 32; m <<= 1) s3 += __shfl_xor(s3, m);
        float inv = 1.f / fmaxf(sqrtf(s3), 1e-12f);
#pragma unroll
        for (int j = 0; j < 4; ++j)
            out[(size_t)(row0 + r) * 128 + cg + 32 * j] = y[j] * inv;
    }
}

// =====================================================================
// K2: K[b,n,m] = exp(-clip(1 - Sp[b,n].Fp[b,m],0,2)/0.1)
// =====================================================================
__global__ __launch_bounds__(256) void cosk_kernel(const float* __restrict__ SP,
                                                   const float* __restrict__ FP,
                                                   float* __restrict__ Kout,
                                                   half_t* __restrict__ K16out) {
    const int b = blockIdx.y;
    const int tile = blockIdx.x;
    const int n0 = (tile >> 3) * 64, m0 = (tile & 7) * 64;
    __shared__ float sA[64 * 66];
    __shared__ float sB[64 * 66];
    const float* A  = SP + (size_t)b * NTOK * PDIM;
    const float* Bm = FP + (size_t)b * NTOK * PDIM;
    const int t = threadIdx.x;
    const int mg = t & 15, ng = t >> 4;
    float acc[4][4] = {};

    for (int kc = 0; kc < 2; ++kc) {   // 2 k-chunks of 64 (PDIM=128)
#pragma unroll
        for (int i = 0; i < 4; ++i) {
            int e = t + 256 * i;           // 0..1023
            int r = e >> 4, k4 = (e & 15) * 4;
            float4 va = *(const float4*)&A [(size_t)(n0 + r) * 128 + kc * 64 + k4];
            float4 vb = *(const float4*)&Bm[(size_t)(m0 + r) * 128 + kc * 64 + k4];
            float* da = &sA[r * 66 + k4];
            da[0] = va.x; da[1] = va.y; da[2] = va.z; da[3] = va.w;
            float* db = &sB[r * 66 + k4];
            db[0] = vb.x; db[1] = vb.y; db[2] = vb.z; db[3] = vb.w;
        }
        __syncthreads();
#pragma unroll 8
        for (int kk = 0; kk < 64; kk += 2) {
            float2 a2[4], b2[4];
#pragma unroll
            for (int i = 0; i < 4; ++i) a2[i] = *(const float2*)&sA[(ng + 16 * i) * 66 + kk];
#pragma unroll
            for (int j = 0; j < 4; ++j) b2[j] = *(const float2*)&sB[(mg + 16 * j) * 66 + kk];
#pragma unroll
            for (int i = 0; i < 4; ++i)
#pragma unroll
                for (int j = 0; j < 4; ++j)
                    acc[i][j] += a2[i].x * b2[j].x + a2[i].y * b2[j].y;
        }
        __syncthreads();
    }

#pragma unroll
    for (int i = 0; i < 4; ++i) {
        int n = n0 + ng + 16 * i;
#pragma unroll
        for (int j = 0; j < 4; ++j) {
            int m = m0 + mg + 16 * j;
            float C = fminf(fmaxf(1.f - acc[i][j], 0.f), 2.f);
            float K = expf(-10.f * C);
            size_t gidx = ((size_t)b * NTOK + n) * NTOK + m;
            Kout[gidx] = K;
            K16out[gidx] = (half_t)K;
        }
    }
}

// =====================================================================
// K3 (cooperative fused Sinkhorn): 256 blocks x 1024 threads, 1/CU.
// Block (b,h): rows h*256..+256 of batch b.  16 waves x 16 rows; the
// 16-row group-of-4 depth-2 streaming loop is the r2-verified code.
// Cross-half col-sum exchange: double-buffered cparts[2][B][2][512]
// (stored in the LDS swizzle order, coalesced both directions) + ONE
// grid.sync() per iteration.  __threadfence before (release) and after
// (acquire/L2-inv) the sync for cross-XCD visibility.
// Deadlock-safe: hipLaunchCooperativeKernel validates co-residency at
// launch (error, not hang, on failure).  256 blocks = 1 per CU.
// LDS: vs 2KB + wacc 32KB = 34KB.  VGPR ~95 < 128 cap (16 waves/CU).
// =====================================================================
__global__ __launch_bounds__(1024) void sinkhorn_coop_kernel(const half_t* __restrict__ K16,
                                                             float* __restrict__ cparts,
                                                             float* __restrict__ U,
                                                             float* __restrict__ VFIN) {
    cg::grid_group grid = cg::this_grid();
    const int blk = blockIdx.x;
    const int b = blk >> 1, h = blk & 1;
    const int t = threadIdx.x;
    const int wave = t >> 6, lane = t & 63;

    __shared__ float vs[NTOK];          // swizzled: vs[sw(m)], sw(m)=(m&7)*64+(m>>3)
    __shared__ float wacc[16][NTOK];    // swizzled cols

    const half_t* Kbase = K16 + ((size_t)b * NTOK + h * 256 + wave * 16) * NTOK + lane * 8;

    float ureg = 0.f;

    for (int it = 0; it < NIT; ++it) {
        // ---- vs phase (threads 0..511, swizzled order; coalesced) ----
        if (it == 0) {
            if (t < NTOK) vs[t] = 1.f;
        } else {
            if (t < NTOK) {
                const float* c0 = cparts + ((size_t)(it & 1) * BSZ * 2 + b * 2) * NTOK;
                float sum = c0[t] + c0[NTOK + t];
                float v = (1.f / 512.f) / (sum + 1e-8f);
                vs[t] = fminf(fmaxf(v, 1e-8f), 1e8f);
            }
        }
        __syncthreads();

        // vl[j] = v[lane*8+j]: swizzled idx j*64+lane -> stride-1/lane
        float vl[8];
#pragma unroll
        for (int j = 0; j < 8; ++j) vl[j] = vs[j * 64 + lane];

        // ---- K stream: 4 groups of 4 rows, depth-2 lookahead (r2-proven) ----
        half8_t buf[3][4];
#pragma unroll
        for (int r = 0; r < 4; ++r) buf[0][r] = *(const half8_t*)(Kbase + (size_t)r * NTOK);
#pragma unroll
        for (int r = 0; r < 4; ++r) buf[1][r] = *(const half8_t*)(Kbase + (size_t)(4 + r) * NTOK);

        float colacc[8] = {};

#pragma unroll
        for (int g = 0; g < 4; ++g) {
            if (g < 2) {
#pragma unroll
                for (int r = 0; r < 4; ++r)
                    buf[(g + 2) % 3][r] = *(const half8_t*)(Kbase + (size_t)((g + 2) * 4 + r) * NTOK);
            }
            float p[4];
#pragma unroll
            for (int rr = 0; rr < 4; ++rr) {
                const half8_t kk = buf[g % 3][rr];
                float d0 = (float)kk[0] * vl[0] + (float)kk[1] * vl[1];
                float d1 = (float)kk[2] * vl[2] + (float)kk[3] * vl[3];
                float d2 = (float)kk[4] * vl[4] + (float)kk[5] * vl[5];
                float d3 = (float)kk[6] * vl[6] + (float)kk[7] * vl[7];
                p[rr] = (d0 + d1) + (d2 + d3);
            }
#pragma unroll
            for (int m = 1; m < 64; m <<= 1)
#pragma unroll
                for (int rr = 0; rr < 4; ++rr)
                    p[rr] += __shfl_xor(p[rr], m);
#pragma unroll
            for (int rr = 0; rr < 4; ++rr) {
                float u_r = (1.f / 512.f) / (p[rr] + 1e-8f);
                if (lane == g * 4 + rr) ureg = u_r;   // lanes 0..15 hold their row's u
#pragma unroll
                for (int j = 0; j < 8; ++j)
                    colacc[j] += (float)buf[g % 3][rr][j] * u_r;
            }
        }
        if (it == NIT - 1 && lane < 16)
            U[(size_t)b * NTOK + h * 256 + wave * 16 + lane] = ureg;   // raw u, clipped in final

        // colacc[j] is col m=lane*8+j -> swizzled j*64+lane (stride-1)
#pragma unroll
        for (int j = 0; j < 8; ++j) wacc[wave][j * 64 + lane] = colacc[j];
        __syncthreads();

        // ---- combine 16 waves -> cparts[(it+1)&1][b][h][:] (swizzled, coalesced) ----
        if (t < NTOK) {
            float sum = 0.f;
#pragma unroll
            for (int w = 0; w < 16; ++w) sum += wacc[w][t];
            cparts[((size_t)((it + 1) & 1) * BSZ * 2 + b * 2 + h) * NTOK + t] = sum;
        }
        __threadfence();   // release: drain stores, write back L2 (cross-XCD)
        grid.sync();
        __threadfence();   // acquire: invalidate L1/L2 before next-iter cparts reads
    }

    // final v from last iteration's colacc (NIT even -> buffer 0)
    if (h == 0 && t < NTOK) {
        const float* c0 = cparts + ((size_t)b * 2) * NTOK;
        float sum = c0[t] + c0[NTOK + t];
        float v = (1.f / 512.f) / (sum + 1e-8f);
        int m = ((t & 63) << 3) | (t >> 6);        // unswizzle
        VFIN[(size_t)b * NTOK + m] = fminf(fmaxf(v, 1e-8f), 1e8f);
    }
}

// =====================================================================
// K5: final (REVERTED to the r2-measured 304us body: 16 rows x 4 cols,
// software-pipelined K-chunk loads, double-buffered sP, float4 LDS
// reads).  Only change vs r2: v comes precomputed (clipped) from VFIN.
// NOTE: FT writes land exactly on this strip's K16 bytes (FT region) --
// K16 is dead after the sinkhorn loop, and final reads only K32.
// =====================================================================
__global__ __launch_bounds__(256, 4) void final_kernel(const float* __restrict__ vfin,
                                                       const float* __restrict__ u,
                                                       const float* __restrict__ F,
                                                       float* __restrict__ Pout,
                                                       float* __restrict__ FTout) {
    const int blk = blockIdx.x;
    const int b = blk >> 3, s = blk & 7;
    __shared__ float vs[NTOK];
    __shared__ float us[64];
    __shared__ float sP[2][64 * 68];
    const int t = threadIdx.x;

    for (int m = t; m < NTOK; m += 256)
        vs[m] = vfin[(size_t)b * NTOK + m];          // already clipped
    if (t < 64) {
        float uu = u[(size_t)b * NTOK + s * 64 + t];
        us[t] = fminf(fmaxf(uu, 1e-8f), 1e8f);
    }

    const int dg = t & 63;   // F cols 4*dg..+4
    const int ng = t >> 6;   // row group: rows 16*ng..+16
    const float* Fb = F + (size_t)b * NTOK * FDIM;
    float* Pbase = Pout + ((size_t)b * NTOK + s * 64) * NTOK;

    float4 kreg[4];
    auto issue_load = [&](int mc) {
#pragma unroll
        for (int i = 0; i < 4; ++i) {
            int e = t + 256 * i;            // 0..1023 float4 slots
            int r = e >> 4, m4 = (e & 15) * 4;
            kreg[i] = *(const float4*)&Pbase[(size_t)r * NTOK + mc * 64 + m4];
        }
    };
    auto emit = [&](int mc, int bufi) {     // P = u*K*v -> global (in place) + LDS
#pragma unroll
        for (int i = 0; i < 4; ++i) {
            int e = t + 256 * i;
            int r = e >> 4, m4 = (e & 15) * 4;
            float ur = us[r];
            float4 p4;
            p4.x = kreg[i].x * ur * vs[mc * 64 + m4 + 0];
            p4.y = kreg[i].y * ur * vs[mc * 64 + m4 + 1];
            p4.z = kreg[i].z * ur * vs[mc * 64 + m4 + 2];
            p4.w = kreg[i].w * ur * vs[mc * 64 + m4 + 3];
            *(float4*)&Pbase[(size_t)r * NTOK + mc * 64 + m4] = p4;
            float* dst = &sP[bufi][r * 68 + m4];
            dst[0] = p4.x; dst[1] = p4.y; dst[2] = p4.z; dst[3] = p4.w;
        }
    };

    float acc[16][4] = {};

    issue_load(0);
    __syncthreads();          // vs/us visible
    emit(0, 0);
    __syncthreads();
    int cur = 0;

    for (int mc = 0; mc < 8; ++mc) {
        if (mc < 7) issue_load(mc + 1);     // next chunk's K in flight during GEMM

        // FT[64,256] += P_chunk[64,64] @ F[mchunk,256], float4 LDS reads
        const float* Fc = Fb + (size_t)(mc * 64) * FDIM + 4 * dg;
        const float* sp = sP[cur];
        for (int mm = 0; mm < 64; mm += 4) {
            float4 f0 = *(const float4*)&Fc[(size_t)(mm + 0) * FDIM];
            float4 f1 = *(const float4*)&Fc[(size_t)(mm + 1) * FDIM];
            float4 f2 = *(const float4*)&Fc[(size_t)(mm + 2) * FDIM];
            float4 f3 = *(const float4*)&Fc[(size_t)(mm + 3) * FDIM];
#pragma unroll
            for (int i = 0; i < 16; ++i) {
                float4 p = *(const float4*)&sp[(ng * 16 + i) * 68 + mm];
                acc[i][0] += p.x * f0.x + p.y * f1.x + p.z * f2.x + p.w * f3.x;
                acc[i][1] += p.x * f0.y + p.y * f1.y + p.z * f2.y + p.w * f3.y;
                acc[i][2] += p.x * f0.z + p.y * f1.z + p.z * f2.z + p.w * f3.z;
                acc[i][3] += p.x * f0.w + p.y * f1.w + p.z * f2.w + p.w * f3.w;
            }
        }

        if (mc < 7) {
            emit(mc + 1, cur ^ 1);
            __syncthreads();
            cur ^= 1;
        }
    }

#pragma unroll
    for (int i = 0; i < 16; ++i) {
        float4 o;
        o.x = acc[i][0]; o.y = acc[i][1]; o.z = acc[i][2]; o.w = acc[i][3];
        *(float4*)&FTout[((size_t)b * NTOK + s * 64 + ng * 16 + i) * FDIM + 4 * dg] = o;
    }
}

// =====================================================================
extern "C" void kernel_launch(void* const* d_in, const int* in_sizes, int n_in,
                              void* d_out, int out_size, void* d_ws, size_t ws_size,
                              hipStream_t stream) {
    const float* S      = (const float*)d_in[0];
    const float* F      = (const float*)d_in[1];
    const float* W_s    = (const float*)d_in[2];
    const float* b_s    = (const float*)d_in[3];
    const float* g_s    = (const float*)d_in[4];
    const float* beta_s = (const float*)d_in[5];
    const float* W_f    = (const float*)d_in[6];
    const float* b_f    = (const float*)d_in[7];
    const float* g_f    = (const float*)d_in[8];
    const float* beta_f = (const float*)d_in[9];

    float* wsf  = (float*)d_ws;
    float* WT_s = wsf;                        // 32768
    float* WT_f = wsf + 32768;                // 32768
    float* SP   = wsf + 65536;                // 65536*128
    float* FP   = SP + (size_t)65536 * 128;   // 65536*128
    float* U    = FP + (size_t)65536 * 128;   // 65536
    float* VFIN = U + 65536;                  // 65536 (final clipped v)
    float* CPARTS = VFIN + 65536;             // 2*128*2*512 = 262144 floats

    float* Pout = (float*)d_out;                      // [128,512,512] (K32 then P, in place)
    float* FT   = Pout + (size_t)BSZ * NTOK * NTOK;   // [128,512,256]
    // fp16 K lives in the FT region during the sinkhorn phase:
    // 128*512*512*2 bytes == 128*512*256*4 bytes exactly.
    half_t* K16 = (half_t*)FT;

    transpose_w_kernel<<<128, 256, 0, stream>>>(W_s, WT_s);
    transpose_w_kernel<<<128, 256, 0, stream>>>(W_f, WT_f);

    proj_kernel<<<2048, 256, 0, stream>>>(S, WT_s, b_s, g_s, beta_s, SP);
    proj_kernel<<<2048, 256, 0, stream>>>(F, WT_f, b_f, g_f, beta_f, FP);

    cosk_kernel<<<dim3(64, 128), 256, 0, stream>>>(SP, FP, Pout, K16);

    // all 30 iterations in ONE cooperative dispatch; 256 blocks = 1/CU.
    {
        const half_t* k16a = K16;
        float* cpa = CPARTS;
        float* ua  = U;
        float* vfa = VFIN;
        void* kargs[] = { (void*)&k16a, (void*)&cpa, (void*)&ua, (void*)&vfa };
        hipLaunchCooperativeKernel((const void*)sinkhorn_coop_kernel,
                                   dim3(256), dim3(1024), kargs, 0, stream);
    }

    final_kernel<<<1024, 256, 0, stream>>>(VFIN, U, F, Pout, FT);
}

// Round 6
// 2209.352 us; speedup vs baseline: 2.8833x; 2.8833x over previous
//
#include <hip/hip_runtime.h>

// Problem constants
#define BSZ   128
#define NTOK  512
#define SDIM  256
#define PDIM  128
#define FDIM  256
#define NIT   30

typedef _Float16 half_t;
typedef _Float16 half8_t __attribute__((ext_vector_type(8)));

// =====================================================================
// K0: transpose W [256,128] -> Wt [128,256]
// =====================================================================
__global__ __launch_bounds__(256) void transpose_w_kernel(const float* __restrict__ W,
                                                          float* __restrict__ Wt) {
    int idx = blockIdx.x * 256 + threadIdx.x;   // [0, 32768)
    int d = idx >> 7;        // 0..255
    int p = idx & 127;       // 0..127
    Wt[p * 256 + d] = W[idx];
}

// =====================================================================
// K1: h = X@W + b -> LayerNorm -> *g+beta -> l2norm.
// =====================================================================
__global__ __launch_bounds__(256) void proj_kernel(const float* __restrict__ X,
                                                   const float* __restrict__ Wt,
                                                   const float* __restrict__ bias,
                                                   const float* __restrict__ gamma,
                                                   const float* __restrict__ beta,
                                                   float* __restrict__ out) {
    __shared__ float sX[32 * 66];
    __shared__ float sB[128 * 66];
    const int t = threadIdx.x;
    const int row0 = blockIdx.x * 32;
    const int cg = t & 31;      // col group
    const int rg = t >> 5;      // 0..7
    float acc[4][4] = {};

    for (int dc = 0; dc < 4; ++dc) {   // 4 k-chunks of 64
#pragma unroll
        for (int i = 0; i < 2; ++i) {  // stage 32x64 X chunk
            int e = t + 256 * i;
            int r = e >> 4, k4 = (e & 15) * 4;
            float4 v = *(const float4*)&X[(size_t)(row0 + r) * 256 + dc * 64 + k4];
            float* dst = &sX[r * 66 + k4];
            dst[0] = v.x; dst[1] = v.y; dst[2] = v.z; dst[3] = v.w;
        }
#pragma unroll
        for (int i = 0; i < 8; ++i) {  // stage 128x64 W chunk
            int e = t + 256 * i;
            int c = e >> 4, k4 = (e & 15) * 4;
            float4 v = *(const float4*)&Wt[(size_t)c * 256 + dc * 64 + k4];
            float* dst = &sB[c * 66 + k4];
            dst[0] = v.x; dst[1] = v.y; dst[2] = v.z; dst[3] = v.w;
        }
        __syncthreads();
#pragma unroll 8
        for (int kk = 0; kk < 64; kk += 2) {
            float2 a2[4], b2[4];
#pragma unroll
            for (int j = 0; j < 4; ++j) b2[j] = *(const float2*)&sB[(cg + 32 * j) * 66 + kk];
#pragma unroll
            for (int i = 0; i < 4; ++i) a2[i] = *(const float2*)&sX[(rg + 8 * i) * 66 + kk];
#pragma unroll
            for (int i = 0; i < 4; ++i)
#pragma unroll
                for (int j = 0; j < 4; ++j)
                    acc[i][j] += a2[i].x * b2[j].x + a2[i].y * b2[j].y;
        }
        __syncthreads();
    }

    float bia[4], gam[4], bet[4];
#pragma unroll
    for (int j = 0; j < 4; ++j) {
        int c = cg + 32 * j;
        bia[j] = bias[c]; gam[j] = gamma[c]; bet[j] = beta[c];
    }

#pragma unroll
    for (int i = 0; i < 4; ++i) {
        int r = rg + 8 * i;
        float h[4];
        float s1 = 0.f, s2 = 0.f;
#pragma unroll
        for (int j = 0; j < 4; ++j) {
            h[j] = acc[i][j] + bia[j];
            s1 += h[j];
            s2 += h[j] * h[j];
        }
        for (int m = 1; m < 32; m <<= 1) {
            s1 += __shfl_xor(s1, m);
            s2 += __shfl_xor(s2, m);
        }
        float mu  = s1 * (1.f / 128.f);
        float var = s2 * (1.f / 128.f) - mu * mu;
        float rstd = 1.f / sqrtf(var + 1e-5f);
        float y[4]; float s3 = 0.f;
#pragma unroll
        for (int j = 0; j < 4; ++j) {
            y[j] = (h[j] - mu) * rstd * gam[j] + bet[j];
            s3 += y[j] * y[j];
        }
        for (int m = 1; m < 32; m <<= 1) s3 += __shfl_xor(s3, m);
        float inv = 1.f / fmaxf(sqrtf(s3), 1e-12f);
#pragma unroll
        for (int j = 0; j < 4; ++j)
            out[(size_t)(row0 + r) * 128 + cg + 32 * j] = y[j] * inv;
    }
}

// =====================================================================
// K2: K[b,n,m] = exp(-clip(1 - Sp[b,n].Fp[b,m],0,2)/0.1)
// =====================================================================
__global__ __launch_bounds__(256) void cosk_kernel(const float* __restrict__ SP,
                                                   const float* __restrict__ FP,
                                                   float* __restrict__ Kout,
                                                   half_t* __restrict__ K16out) {
    const int b = blockIdx.y;
    const int tile = blockIdx.x;
    const int n0 = (tile >> 3) * 64, m0 = (tile & 7) * 64;
    __shared__ float sA[64 * 66];
    __shared__ float sB[64 * 66];
    const float* A  = SP + (size_t)b * NTOK * PDIM;
    const float* Bm = FP + (size_t)b * NTOK * PDIM;
    const int t = threadIdx.x;
    const int mg = t & 15, ng = t >> 4;
    float acc[4][4] = {};

    for (int kc = 0; kc < 2; ++kc) {   // 2 k-chunks of 64 (PDIM=128)
#pragma unroll
        for (int i = 0; i < 4; ++i) {
            int e = t + 256 * i;           // 0..1023
            int r = e >> 4, k4 = (e & 15) * 4;
            float4 va = *(const float4*)&A [(size_t)(n0 + r) * 128 + kc * 64 + k4];
            float4 vb = *(const float4*)&Bm[(size_t)(m0 + r) * 128 + kc * 64 + k4];
            float* da = &sA[r * 66 + k4];
            da[0] = va.x; da[1] = va.y; da[2] = va.z; da[3] = va.w;
            float* db = &sB[r * 66 + k4];
            db[0] = vb.x; db[1] = vb.y; db[2] = vb.z; db[3] = vb.w;
        }
        __syncthreads();
#pragma unroll 8
        for (int kk = 0; kk < 64; kk += 2) {
            float2 a2[4], b2[4];
#pragma unroll
            for (int i = 0; i < 4; ++i) a2[i] = *(const float2*)&sA[(ng + 16 * i) * 66 + kk];
#pragma unroll
            for (int j = 0; j < 4; ++j) b2[j] = *(const float2*)&sB[(mg + 16 * j) * 66 + kk];
#pragma unroll
            for (int i = 0; i < 4; ++i)
#pragma unroll
                for (int j = 0; j < 4; ++j)
                    acc[i][j] += a2[i].x * b2[j].x + a2[i].y * b2[j].y;
        }
        __syncthreads();
    }

#pragma unroll
    for (int i = 0; i < 4; ++i) {
        int n = n0 + ng + 16 * i;
#pragma unroll
        for (int j = 0; j < 4; ++j) {
            int m = m0 + mg + 16 * j;
            float C = fminf(fmaxf(1.f - acc[i][j], 0.f), 2.f);
            float K = expf(-10.f * C);
            size_t gidx = ((size_t)b * NTOK + n) * NTOK + m;
            Kout[gidx] = K;
            K16out[gidx] = (half_t)K;
        }
    }
}

// =====================================================================
// K3 (FUSED 30-iter Sinkhorn with on-CU K residency): 128 blocks x 1024.
// Block b owns batch element b.  Wave w owns rows w*32..+31:
//   rows  0..7  -> VGPR stash kreg[8]      (32 VGPR, filled at iter 0)
//   rows  8..15 -> LDS stash klds[w][8][512] (128 KB/block, filled iter 0)
//   rows 16..31 -> streamed from HBM each iter, depth-3 prefetch
// HBM traffic: 67 MB (iter0) + 29 x 32 MB ~= 1.0 GB (was 2.03 GB in r4).
// wacc reduced to [8][512] via two-phase combine (waves 8..15 add into
// waves 0..7 slots) to fit LDS: 128 + 16 + 2 = 146 KB <= 160 KB.
// Row order 0..31 ascending -> per-row math identical to r4 (passed).
// Intra-block sync ONLY (r5 lesson: grid.sync costs ~180us/iter).
// __launch_bounds__(1024,4): VGPR cap 128; body ~110 (kreg 32 + hbuf 48
// + scalars) -- no spill expected; watch VGPR_Count/regression if not.
// =====================================================================
__global__ __launch_bounds__(1024, 4) void sinkhorn_fused_kernel(const half_t* __restrict__ K16,
                                                                 float* __restrict__ U,
                                                                 float* __restrict__ VFIN) {
    const int b = blockIdx.x;
    const int t = threadIdx.x;
    const int wave = t >> 6, lane = t & 63;    // wave 0..15

    __shared__ float  vs[NTOK];                // swizzled: vs[sw(m)], sw(m)=(m&7)*64+(m>>3)
    __shared__ float  wacc[8][NTOK];           // swizzled cols; 16 KB
    __shared__ half_t klds[16][8][NTOK];       // per-wave LDS row stash; 128 KB

    const half_t* Kbase = K16 + ((size_t)b * NTOK + wave * 32) * NTOK + lane * 8;

    if (t < NTOK) vs[t] = 1.f;                 // v0 = ones (swizzle-invariant)
    __syncthreads();

    half8_t kreg[8];                            // rows 0..7 (constant-indexed only)
    float ureg = 0.f;

    for (int it = 0; it < NIT; ++it) {
        // vl[j] = v[lane*8+j]; swizzled idx j*64+lane -> stride-1 per lane
        float vl[8];
#pragma unroll
        for (int j = 0; j < 8; ++j) vl[j] = vs[j * 64 + lane];

        float colacc[8] = {};

        // process 4 rows (values k0..k3, absolute base row r0 within wave)
        auto proc4 = [&](half8_t k0, half8_t k1, half8_t k2, half8_t k3, int r0) {
            half8_t kk[4] = { k0, k1, k2, k3 };
            float p[4];
#pragma unroll
            for (int rr = 0; rr < 4; ++rr) {
                float d0 = (float)kk[rr][0] * vl[0] + (float)kk[rr][1] * vl[1];
                float d1 = (float)kk[rr][2] * vl[2] + (float)kk[rr][3] * vl[3];
                float d2 = (float)kk[rr][4] * vl[4] + (float)kk[rr][5] * vl[5];
                float d3 = (float)kk[rr][6] * vl[6] + (float)kk[rr][7] * vl[7];
                p[rr] = (d0 + d1) + (d2 + d3);
            }
#pragma unroll
            for (int m = 1; m < 64; m <<= 1)
#pragma unroll
                for (int rr = 0; rr < 4; ++rr)
                    p[rr] += __shfl_xor(p[rr], m);
#pragma unroll
            for (int rr = 0; rr < 4; ++rr) {
                float u_r = (1.f / 512.f) / (p[rr] + 1e-8f);
                if (lane == r0 + rr) ureg = u_r;   // lanes 0..31 collect their row's u
#pragma unroll
                for (int j = 0; j < 8; ++j)
                    colacc[j] += (float)kk[rr][j] * u_r;
            }
        };

        if (it == 0) {
            // stream ALL 32 rows (r4-proven rolling buf) and stash rows 0..15
            half8_t buf[3][4];
#pragma unroll
            for (int r = 0; r < 4; ++r) buf[0][r] = *(const half8_t*)(Kbase + (size_t)r * NTOK);
#pragma unroll
            for (int r = 0; r < 4; ++r) buf[1][r] = *(const half8_t*)(Kbase + (size_t)(4 + r) * NTOK);
#pragma unroll
            for (int g = 0; g < 8; ++g) {
                if (g < 6) {
#pragma unroll
                    for (int r = 0; r < 4; ++r)
                        buf[(g + 2) % 3][r] = *(const half8_t*)(Kbase + (size_t)((g + 2) * 4 + r) * NTOK);
                }
                proc4(buf[g % 3][0], buf[g % 3][1], buf[g % 3][2], buf[g % 3][3], g * 4);
#pragma unroll
                for (int rr = 0; rr < 4; ++rr) {
                    const int row = g * 4 + rr;          // compile-time (unrolled)
                    if (row < 8)
                        kreg[row] = buf[g % 3][rr];
                    else if (row < 16)
                        *(half8_t*)&klds[wave][row - 8][lane * 8] = buf[g % 3][rr];
                }
            }
        } else {
            // issue all 12 prefetch loads for HBM rows 16..27 up front
            half8_t ha[4], hb[4], hc[4];
#pragma unroll
            for (int r = 0; r < 4; ++r) ha[r] = *(const half8_t*)(Kbase + (size_t)(16 + r) * NTOK);
#pragma unroll
            for (int r = 0; r < 4; ++r) hb[r] = *(const half8_t*)(Kbase + (size_t)(20 + r) * NTOK);
#pragma unroll
            for (int r = 0; r < 4; ++r) hc[r] = *(const half8_t*)(Kbase + (size_t)(24 + r) * NTOK);

            proc4(kreg[0], kreg[1], kreg[2], kreg[3], 0);     // G0: regs
            proc4(kreg[4], kreg[5], kreg[6], kreg[7], 4);     // G1: regs

            half8_t l0[4];
#pragma unroll
            for (int r = 0; r < 4; ++r) l0[r] = *(const half8_t*)&klds[wave][r][lane * 8];
            proc4(l0[0], l0[1], l0[2], l0[3], 8);             // G2: LDS

            half8_t l1[4];
#pragma unroll
            for (int r = 0; r < 4; ++r) l1[r] = *(const half8_t*)&klds[wave][4 + r][lane * 8];
            proc4(l1[0], l1[1], l1[2], l1[3], 12);            // G3: LDS

            proc4(ha[0], ha[1], ha[2], ha[3], 16);            // G4: HBM
#pragma unroll
            for (int r = 0; r < 4; ++r) ha[r] = *(const half8_t*)(Kbase + (size_t)(28 + r) * NTOK);
            proc4(hb[0], hb[1], hb[2], hb[3], 20);            // G5: HBM
            proc4(hc[0], hc[1], hc[2], hc[3], 24);            // G6: HBM
            proc4(ha[0], ha[1], ha[2], ha[3], 28);            // G7: HBM
        }

        // ---- two-phase 16-wave combine into wacc[8] (swizzled, stride-1) ----
        if (wave < 8) {
#pragma unroll
            for (int j = 0; j < 8; ++j) wacc[wave][j * 64 + lane] = colacc[j];
        }
        __syncthreads();
        if (wave >= 8) {
#pragma unroll
            for (int j = 0; j < 8; ++j) wacc[wave - 8][j * 64 + lane] += colacc[j];
        }
        __syncthreads();

        // ---- v update (threads 0..511, conflict-free) ----
        if (t < NTOK) {
            float sum = 0.f;
#pragma unroll
            for (int w = 0; w < 8; ++w) sum += wacc[w][t];
            float v = (1.f / 512.f) / (sum + 1e-8f);
            v = fminf(fmaxf(v, 1e-8f), 1e8f);
            if (it < NIT - 1) {
                vs[t] = v;
            } else {
                int m = ((t & 63) << 3) | (t >> 6);      // unswizzle
                VFIN[(size_t)b * NTOK + m] = v;          // final clipped v
            }
        }
        if (it == NIT - 1 && lane < 32)
            U[(size_t)b * NTOK + wave * 32 + lane] = ureg;   // raw u (clip in final)
        __syncthreads();   // vs visible / wacc reusable
    }
}

// =====================================================================
// K5: final (r2-measured 304us body: 16 rows x 4 cols, software-
// pipelined K-chunk loads, double-buffered sP, float4 LDS reads).
// v comes precomputed (clipped) from VFIN.
// NOTE: FT writes land exactly on this strip's K16 bytes (FT region) --
// K16 is dead after the sinkhorn loop, and final reads only K32.
// =====================================================================
__global__ __launch_bounds__(256, 4) void final_kernel(const float* __restrict__ vfin,
                                                       const float* __restrict__ u,
                                                       const float* __restrict__ F,
                                                       float* __restrict__ Pout,
                                                       float* __restrict__ FTout) {
    const int blk = blockIdx.x;
    const int b = blk >> 3, s = blk & 7;
    __shared__ float vs[NTOK];
    __shared__ float us[64];
    __shared__ float sP[2][64 * 68];
    const int t = threadIdx.x;

    for (int m = t; m < NTOK; m += 256)
        vs[m] = vfin[(size_t)b * NTOK + m];          // already clipped
    if (t < 64) {
        float uu = u[(size_t)b * NTOK + s * 64 + t];
        us[t] = fminf(fmaxf(uu, 1e-8f), 1e8f);
    }

    const int dg = t & 63;   // F cols 4*dg..+4
    const int ng = t >> 6;   // row group: rows 16*ng..+16
    const float* Fb = F + (size_t)b * NTOK * FDIM;
    float* Pbase = Pout + ((size_t)b * NTOK + s * 64) * NTOK;

    float4 kreg[4];
    auto issue_load = [&](int mc) {
#pragma unroll
        for (int i = 0; i < 4; ++i) {
            int e = t + 256 * i;            // 0..1023 float4 slots
            int r = e >> 4, m4 = (e & 15) * 4;
            kreg[i] = *(const float4*)&Pbase[(size_t)r * NTOK + mc * 64 + m4];
        }
    };
    auto emit = [&](int mc, int bufi) {     // P = u*K*v -> global (in place) + LDS
#pragma unroll
        for (int i = 0; i < 4; ++i) {
            int e = t + 256 * i;
            int r = e >> 4, m4 = (e & 15) * 4;
            float ur = us[r];
            float4 p4;
            p4.x = kreg[i].x * ur * vs[mc * 64 + m4 + 0];
            p4.y = kreg[i].y * ur * vs[mc * 64 + m4 + 1];
            p4.z = kreg[i].z * ur * vs[mc * 64 + m4 + 2];
            p4.w = kreg[i].w * ur * vs[mc * 64 + m4 + 3];
            *(float4*)&Pbase[(size_t)r * NTOK + mc * 64 + m4] = p4;
            float* dst = &sP[bufi][r * 68 + m4];
            dst[0] = p4.x; dst[1] = p4.y; dst[2] = p4.z; dst[3] = p4.w;
        }
    };

    float acc[16][4] = {};

    issue_load(0);
    __syncthreads();          // vs/us visible
    emit(0, 0);
    __syncthreads();
    int cur = 0;

    for (int mc = 0; mc < 8; ++mc) {
        if (mc < 7) issue_load(mc + 1);     // next chunk's K in flight during GEMM

        // FT[64,256] += P_chunk[64,64] @ F[mchunk,256], float4 LDS reads
        const float* Fc = Fb + (size_t)(mc * 64) * FDIM + 4 * dg;
        const float* sp = sP[cur];
        for (int mm = 0; mm < 64; mm += 4) {
            float4 f0 = *(const float4*)&Fc[(size_t)(mm + 0) * FDIM];
            float4 f1 = *(const float4*)&Fc[(size_t)(mm + 1) * FDIM];
            float4 f2 = *(const float4*)&Fc[(size_t)(mm + 2) * FDIM];
            float4 f3 = *(const float4*)&Fc[(size_t)(mm + 3) * FDIM];
#pragma unroll
            for (int i = 0; i < 16; ++i) {
                float4 p = *(const float4*)&sp[(ng * 16 + i) * 68 + mm];
                acc[i][0] += p.x * f0.x + p.y * f1.x + p.z * f2.x + p.w * f3.x;
                acc[i][1] += p.x * f0.y + p.y * f1.y + p.z * f2.y + p.w * f3.y;
                acc[i][2] += p.x * f0.z + p.y * f1.z + p.z * f2.z + p.w * f3.z;
                acc[i][3] += p.x * f0.w + p.y * f1.w + p.z * f2.w + p.w * f3.w;
            }
        }

        if (mc < 7) {
            emit(mc + 1, cur ^ 1);
            __syncthreads();
            cur ^= 1;
        }
    }

#pragma unroll
    for (int i = 0; i < 16; ++i) {
        float4 o;
        o.x = acc[i][0]; o.y = acc[i][1]; o.z = acc[i][2]; o.w = acc[i][3];
        *(float4*)&FTout[((size_t)b * NTOK + s * 64 + ng * 16 + i) * FDIM + 4 * dg] = o;
    }
}

// =====================================================================
extern "C" void kernel_launch(void* const* d_in, const int* in_sizes, int n_in,
                              void* d_out, int out_size, void* d_ws, size_t ws_size,
                              hipStream_t stream) {
    const float* S      = (const float*)d_in[0];
    const float* F      = (const float*)d_in[1];
    const float* W_s    = (const float*)d_in[2];
    const float* b_s    = (const float*)d_in[3];
    const float* g_s    = (const float*)d_in[4];
    const float* beta_s = (const float*)d_in[5];
    const float* W_f    = (const float*)d_in[6];
    const float* b_f    = (const float*)d_in[7];
    const float* g_f    = (const float*)d_in[8];
    const float* beta_f = (const float*)d_in[9];

    float* wsf  = (float*)d_ws;
    float* WT_s = wsf;                        // 32768
    float* WT_f = wsf + 32768;                // 32768
    float* SP   = wsf + 65536;                // 65536*128
    float* FP   = SP + (size_t)65536 * 128;   // 65536*128
    float* U    = FP + (size_t)65536 * 128;   // 65536
    float* VFIN = U + 65536;                  // 65536 (final clipped v)

    float* Pout = (float*)d_out;                      // [128,512,512] (K32 then P, in place)
    float* FT   = Pout + (size_t)BSZ * NTOK * NTOK;   // [128,512,256]
    // fp16 K lives in the FT region during the sinkhorn phase:
    // 128*512*512*2 bytes == 128*512*256*4 bytes exactly.
    half_t* K16 = (half_t*)FT;

    transpose_w_kernel<<<128, 256, 0, stream>>>(W_s, WT_s);
    transpose_w_kernel<<<128, 256, 0, stream>>>(W_f, WT_f);

    proj_kernel<<<2048, 256, 0, stream>>>(S, WT_s, b_s, g_s, beta_s, SP);
    proj_kernel<<<2048, 256, 0, stream>>>(F, WT_f, b_f, g_f, beta_f, FP);

    cosk_kernel<<<dim3(64, 128), 256, 0, stream>>>(SP, FP, Pout, K16);

    // all 30 iterations in ONE dispatch; block b owns batch element b;
    // intra-block sync only (no grid.sync, no spin).
    sinkhorn_fused_kernel<<<128, 1024, 0, stream>>>(K16, U, VFIN);

    final_kernel<<<1024, 256, 0, stream>>>(VFIN, U, F, Pout, FT);
}

// Round 7
// 1694.805 us; speedup vs baseline: 3.7587x; 1.3036x over previous
//
#include <hip/hip_runtime.h>

// Problem constants
#define BSZ   128
#define NTOK  512
#define SDIM  256
#define PDIM  128
#define FDIM  256
#define NIT   30

typedef _Float16 half_t;
typedef _Float16 half8_t __attribute__((ext_vector_type(8)));

// =====================================================================
// K0: transpose W [256,128] -> Wt [128,256]
// =====================================================================
__global__ __launch_bounds__(256) void transpose_w_kernel(const float* __restrict__ W,
                                                          float* __restrict__ Wt) {
    int idx = blockIdx.x * 256 + threadIdx.x;   // [0, 32768)
    int d = idx >> 7;        // 0..255
    int p = idx & 127;       // 0..127
    Wt[p * 256 + d] = W[idx];
}

// =====================================================================
// K1: h = X@W + b -> LayerNorm -> *g+beta -> l2norm.
// =====================================================================
__global__ __launch_bounds__(256) void proj_kernel(const float* __restrict__ X,
                                                   const float* __restrict__ Wt,
                                                   const float* __restrict__ bias,
                                                   const float* __restrict__ gamma,
                                                   const float* __restrict__ beta,
                                                   float* __restrict__ out) {
    __shared__ float sX[32 * 66];
    __shared__ float sB[128 * 66];
    const int t = threadIdx.x;
    const int row0 = blockIdx.x * 32;
    const int cg = t & 31;      // col group
    const int rg = t >> 5;      // 0..7
    float acc[4][4] = {};

    for (int dc = 0; dc < 4; ++dc) {   // 4 k-chunks of 64
#pragma unroll
        for (int i = 0; i < 2; ++i) {  // stage 32x64 X chunk
            int e = t + 256 * i;
            int r = e >> 4, k4 = (e & 15) * 4;
            float4 v = *(const float4*)&X[(size_t)(row0 + r) * 256 + dc * 64 + k4];
            float* dst = &sX[r * 66 + k4];
            dst[0] = v.x; dst[1] = v.y; dst[2] = v.z; dst[3] = v.w;
        }
#pragma unroll
        for (int i = 0; i < 8; ++i) {  // stage 128x64 W chunk
            int e = t + 256 * i;
            int c = e >> 4, k4 = (e & 15) * 4;
            float4 v = *(const float4*)&Wt[(size_t)c * 256 + dc * 64 + k4];
            float* dst = &sB[c * 66 + k4];
            dst[0] = v.x; dst[1] = v.y; dst[2] = v.z; dst[3] = v.w;
        }
        __syncthreads();
#pragma unroll 8
        for (int kk = 0; kk < 64; kk += 2) {
            float2 a2[4], b2[4];
#pragma unroll
            for (int j = 0; j < 4; ++j) b2[j] = *(const float2*)&sB[(cg + 32 * j) * 66 + kk];
#pragma unroll
            for (int i = 0; i < 4; ++i) a2[i] = *(const float2*)&sX[(rg + 8 * i) * 66 + kk];
#pragma unroll
            for (int i = 0; i < 4; ++i)
#pragma unroll
                for (int j = 0; j < 4; ++j)
                    acc[i][j] += a2[i].x * b2[j].x + a2[i].y * b2[j].y;
        }
        __syncthreads();
    }

    float bia[4], gam[4], bet[4];
#pragma unroll
    for (int j = 0; j < 4; ++j) {
        int c = cg + 32 * j;
        bia[j] = bias[c]; gam[j] = gamma[c]; bet[j] = beta[c];
    }

#pragma unroll
    for (int i = 0; i < 4; ++i) {
        int r = rg + 8 * i;
        float h[4];
        float s1 = 0.f, s2 = 0.f;
#pragma unroll
        for (int j = 0; j < 4; ++j) {
            h[j] = acc[i][j] + bia[j];
            s1 += h[j];
            s2 += h[j] * h[j];
        }
        for (int m = 1; m < 32; m <<= 1) {
            s1 += __shfl_xor(s1, m);
            s2 += __shfl_xor(s2, m);
        }
        float mu  = s1 * (1.f / 128.f);
        float var = s2 * (1.f / 128.f) - mu * mu;
        float rstd = 1.f / sqrtf(var + 1e-5f);
        float y[4]; float s3 = 0.f;
#pragma unroll
        for (int j = 0; j < 4; ++j) {
            y[j] = (h[j] - mu) * rstd * gam[j] + bet[j];
            s3 += y[j] * y[j];
        }
        for (int m = 1; m < 32; m <<= 1) s3 += __shfl_xor(s3, m);
        float inv = 1.f / fmaxf(sqrtf(s3), 1e-12f);
#pragma unroll
        for (int j = 0; j < 4; ++j)
            out[(size_t)(row0 + r) * 128 + cg + 32 * j] = y[j] * inv;
    }
}

// =====================================================================
// K2: K[b,n,m] = exp(-clip(1 - Sp[b,n].Fp[b,m],0,2)/0.1)
// =====================================================================
__global__ __launch_bounds__(256) void cosk_kernel(const float* __restrict__ SP,
                                                   const float* __restrict__ FP,
                                                   float* __restrict__ Kout,
                                                   half_t* __restrict__ K16out) {
    const int b = blockIdx.y;
    const int tile = blockIdx.x;
    const int n0 = (tile >> 3) * 64, m0 = (tile & 7) * 64;
    __shared__ float sA[64 * 66];
    __shared__ float sB[64 * 66];
    const float* A  = SP + (size_t)b * NTOK * PDIM;
    const float* Bm = FP + (size_t)b * NTOK * PDIM;
    const int t = threadIdx.x;
    const int mg = t & 15, ng = t >> 4;
    float acc[4][4] = {};

    for (int kc = 0; kc < 2; ++kc) {   // 2 k-chunks of 64 (PDIM=128)
#pragma unroll
        for (int i = 0; i < 4; ++i) {
            int e = t + 256 * i;           // 0..1023
            int r = e >> 4, k4 = (e & 15) * 4;
            float4 va = *(const float4*)&A [(size_t)(n0 + r) * 128 + kc * 64 + k4];
            float4 vb = *(const float4*)&Bm[(size_t)(m0 + r) * 128 + kc * 64 + k4];
            float* da = &sA[r * 66 + k4];
            da[0] = va.x; da[1] = va.y; da[2] = va.z; da[3] = va.w;
            float* db = &sB[r * 66 + k4];
            db[0] = vb.x; db[1] = vb.y; db[2] = vb.z; db[3] = vb.w;
        }
        __syncthreads();
#pragma unroll 8
        for (int kk = 0; kk < 64; kk += 2) {
            float2 a2[4], b2[4];
#pragma unroll
            for (int i = 0; i < 4; ++i) a2[i] = *(const float2*)&sA[(ng + 16 * i) * 66 + kk];
#pragma unroll
            for (int j = 0; j < 4; ++j) b2[j] = *(const float2*)&sB[(mg + 16 * j) * 66 + kk];
#pragma unroll
            for (int i = 0; i < 4; ++i)
#pragma unroll
                for (int j = 0; j < 4; ++j)
                    acc[i][j] += a2[i].x * b2[j].x + a2[i].y * b2[j].y;
        }
        __syncthreads();
    }

#pragma unroll
    for (int i = 0; i < 4; ++i) {
        int n = n0 + ng + 16 * i;
#pragma unroll
        for (int j = 0; j < 4; ++j) {
            int m = m0 + mg + 16 * j;
            float C = fminf(fmaxf(1.f - acc[i][j], 0.f), 2.f);
            float K = expf(-10.f * C);
            size_t gidx = ((size_t)b * NTOK + n) * NTOK + m;
            Kout[gidx] = K;
            K16out[gidx] = (half_t)K;
        }
    }
}

// =====================================================================
// DPP wave64 sum-reduction on the VALU pipe (rocPRIM canonical form).
// Total lands in lane 63; readlane(63) -> uniform SGPR for all lanes.
// Replaces the 6-step __shfl_xor butterfly (DS pipe, ~30cyc/step) with
// 6 VALU dpp-adds (~4cyc dependent latency each).
// =====================================================================
__device__ __forceinline__ float wave_reduce_add(float x) {
    float t;
    t = __int_as_float(__builtin_amdgcn_update_dpp(0, __float_as_int(x), 0x111, 0xf, 0xf, false)); x += t; // row_shr:1
    t = __int_as_float(__builtin_amdgcn_update_dpp(0, __float_as_int(x), 0x112, 0xf, 0xf, false)); x += t; // row_shr:2
    t = __int_as_float(__builtin_amdgcn_update_dpp(0, __float_as_int(x), 0x114, 0xf, 0xe, false)); x += t; // row_shr:4
    t = __int_as_float(__builtin_amdgcn_update_dpp(0, __float_as_int(x), 0x118, 0xf, 0xc, false)); x += t; // row_shr:8
    t = __int_as_float(__builtin_amdgcn_update_dpp(0, __float_as_int(x), 0x142, 0xa, 0xf, false)); x += t; // row_bcast:15
    t = __int_as_float(__builtin_amdgcn_update_dpp(0, __float_as_int(x), 0x143, 0xc, 0xf, false)); x += t; // row_bcast:31
    return __int_as_float(__builtin_amdgcn_readlane(__float_as_int(x), 63));
}

// =====================================================================
// K3 (FUSED 30-iter Sinkhorn): 128 blocks x 1024 threads, intra-block
// sync only.  Wave w owns rows w*32..+31 of batch b:
//   rows  0..7  -> kreg[8] VGPR stash   (32 VGPR; cap is now 128: the
//                  r6 spill was the __launch_bounds__(,4) 64-VGPR cap)
//   rows  8..23 -> streamed, r4-proven depth-2 rolling buf[3][4]
//   rows 24..31 -> klds LDS stash (128 KB/block)
// Row order 0..31 ascending (accumulation order preserved vs r4).
// Row-dot reduction on VALU via DPP (r4/r6 profile: DS-chain-bound).
// LDS: klds 128K + wacc[8] 16K + vs 2K = 146K <= 160K.
// =====================================================================
__global__ __launch_bounds__(1024) void sinkhorn_fused_kernel(const half_t* __restrict__ K16,
                                                              float* __restrict__ U,
                                                              float* __restrict__ VFIN) {
    const int b = blockIdx.x;
    const int t = threadIdx.x;
    const int wave = t >> 6, lane = t & 63;    // wave 0..15

    __shared__ float  vs[NTOK];                // swizzled: vs[sw(m)], sw(m)=(m&7)*64+(m>>3)
    __shared__ float  wacc[8][NTOK];           // swizzled cols; 16 KB
    __shared__ half_t klds[16][8][NTOK];       // rows 24..31 per wave; 128 KB

    const half_t* Kbase = K16 + ((size_t)b * NTOK + wave * 32) * NTOK + lane * 8;

    if (t < NTOK) vs[t] = 1.f;                 // v0 = ones (swizzle-invariant)
    __syncthreads();

    half8_t kreg[8];                           // rows 0..7 (compile-time indexed only)
    float ureg = 0.f;

    for (int it = 0; it < NIT; ++it) {
        float vl[8];
#pragma unroll
        for (int j = 0; j < 8; ++j) vl[j] = vs[j * 64 + lane];

        float colacc[8] = {};

        // process 4 rows; row-dot partial -> DPP reduce -> uniform u_r
        auto proc4 = [&](half8_t k0, half8_t k1, half8_t k2, half8_t k3, int r0) {
            half8_t kk[4] = { k0, k1, k2, k3 };
            float p[4];
#pragma unroll
            for (int rr = 0; rr < 4; ++rr) {
                float d0 = (float)kk[rr][0] * vl[0] + (float)kk[rr][1] * vl[1];
                float d1 = (float)kk[rr][2] * vl[2] + (float)kk[rr][3] * vl[3];
                float d2 = (float)kk[rr][4] * vl[4] + (float)kk[rr][5] * vl[5];
                float d3 = (float)kk[rr][6] * vl[6] + (float)kk[rr][7] * vl[7];
                p[rr] = (d0 + d1) + (d2 + d3);
            }
            float s[4];
#pragma unroll
            for (int rr = 0; rr < 4; ++rr) s[rr] = wave_reduce_add(p[rr]);
#pragma unroll
            for (int rr = 0; rr < 4; ++rr) {
                float u_r = (1.f / 512.f) / (s[rr] + 1e-8f);   // uniform (sgpr)
                if (lane == r0 + rr) ureg = u_r;
#pragma unroll
                for (int j = 0; j < 8; ++j)
                    colacc[j] += (float)kk[rr][j] * u_r;
            }
        };

        if (it == 0) {
            // stream ALL 32 rows (r4 rolling), stash rows 0..7 and 24..31
            half8_t buf[3][4];
#pragma unroll
            for (int r = 0; r < 4; ++r) buf[0][r] = *(const half8_t*)(Kbase + (size_t)r * NTOK);
#pragma unroll
            for (int r = 0; r < 4; ++r) buf[1][r] = *(const half8_t*)(Kbase + (size_t)(4 + r) * NTOK);
#pragma unroll
            for (int g = 0; g < 8; ++g) {
                if (g < 6) {
#pragma unroll
                    for (int r = 0; r < 4; ++r)
                        buf[(g + 2) % 3][r] = *(const half8_t*)(Kbase + (size_t)((g + 2) * 4 + r) * NTOK);
                }
                proc4(buf[g % 3][0], buf[g % 3][1], buf[g % 3][2], buf[g % 3][3], g * 4);
#pragma unroll
                for (int rr = 0; rr < 4; ++rr) {
                    const int row = g * 4 + rr;            // compile-time (unrolled)
                    if (row < 8)
                        kreg[row] = buf[g % 3][rr];
                    else if (row >= 24)
                        *(half8_t*)&klds[wave][row - 24][lane * 8] = buf[g % 3][rr];
                }
            }
        } else {
            half8_t buf[3][4];
            // prologue: stream rows 8..15 in flight
#pragma unroll
            for (int r = 0; r < 4; ++r) buf[0][r] = *(const half8_t*)(Kbase + (size_t)(8 + r) * NTOK);
#pragma unroll
            for (int r = 0; r < 4; ++r) buf[1][r] = *(const half8_t*)(Kbase + (size_t)(12 + r) * NTOK);

            proc4(kreg[0], kreg[1], kreg[2], kreg[3], 0);          // rows 0-3 (reg)
#pragma unroll
            for (int r = 0; r < 4; ++r) buf[2][r] = *(const half8_t*)(Kbase + (size_t)(16 + r) * NTOK);
            proc4(kreg[4], kreg[5], kreg[6], kreg[7], 4);          // rows 4-7 (reg)

            proc4(buf[0][0], buf[0][1], buf[0][2], buf[0][3], 8);  // rows 8-11
#pragma unroll
            for (int r = 0; r < 4; ++r) buf[0][r] = *(const half8_t*)(Kbase + (size_t)(20 + r) * NTOK);
            proc4(buf[1][0], buf[1][1], buf[1][2], buf[1][3], 12); // rows 12-15
            proc4(buf[2][0], buf[2][1], buf[2][2], buf[2][3], 16); // rows 16-19
            proc4(buf[0][0], buf[0][1], buf[0][2], buf[0][3], 20); // rows 20-23

            // LDS-stashed rows 24..31
            half8_t l0[4], l1[4];
#pragma unroll
            for (int r = 0; r < 4; ++r) l0[r] = *(const half8_t*)&klds[wave][r][lane * 8];
#pragma unroll
            for (int r = 0; r < 4; ++r) l1[r] = *(const half8_t*)&klds[wave][4 + r][lane * 8];
            proc4(l0[0], l0[1], l0[2], l0[3], 24);                 // rows 24-27
            proc4(l1[0], l1[1], l1[2], l1[3], 28);                 // rows 28-31
        }

        // ---- two-phase 16-wave combine into wacc[8] (swizzled, stride-1) ----
        if (wave < 8) {
#pragma unroll
            for (int j = 0; j < 8; ++j) wacc[wave][j * 64 + lane] = colacc[j];
        }
        __syncthreads();
        if (wave >= 8) {
#pragma unroll
            for (int j = 0; j < 8; ++j) wacc[wave - 8][j * 64 + lane] += colacc[j];
        }
        __syncthreads();

        // ---- v update (threads 0..511, conflict-free) ----
        if (t < NTOK) {
            float sum = 0.f;
#pragma unroll
            for (int w = 0; w < 8; ++w) sum += wacc[w][t];
            float v = (1.f / 512.f) / (sum + 1e-8f);
            v = fminf(fmaxf(v, 1e-8f), 1e8f);
            if (it < NIT - 1) {
                vs[t] = v;
            } else {
                int m = ((t & 63) << 3) | (t >> 6);      // unswizzle
                VFIN[(size_t)b * NTOK + m] = v;          // final clipped v
            }
        }
        if (it == NIT - 1 && lane < 32)
            U[(size_t)b * NTOK + wave * 32 + lane] = ureg;   // raw u (clip in final)
        __syncthreads();   // vs visible / wacc reusable
    }
}

// =====================================================================
// K5: final (r2-measured 304us body: 16 rows x 4 cols, software-
// pipelined K-chunk loads, double-buffered sP, float4 LDS reads).
// v comes precomputed (clipped) from VFIN.
// NOTE: FT writes land exactly on this strip's K16 bytes (FT region) --
// K16 is dead after the sinkhorn loop, and final reads only K32.
// =====================================================================
__global__ __launch_bounds__(256, 4) void final_kernel(const float* __restrict__ vfin,
                                                       const float* __restrict__ u,
                                                       const float* __restrict__ F,
                                                       float* __restrict__ Pout,
                                                       float* __restrict__ FTout) {
    const int blk = blockIdx.x;
    const int b = blk >> 3, s = blk & 7;
    __shared__ float vs[NTOK];
    __shared__ float us[64];
    __shared__ float sP[2][64 * 68];
    const int t = threadIdx.x;

    for (int m = t; m < NTOK; m += 256)
        vs[m] = vfin[(size_t)b * NTOK + m];          // already clipped
    if (t < 64) {
        float uu = u[(size_t)b * NTOK + s * 64 + t];
        us[t] = fminf(fmaxf(uu, 1e-8f), 1e8f);
    }

    const int dg = t & 63;   // F cols 4*dg..+4
    const int ng = t >> 6;   // row group: rows 16*ng..+16
    const float* Fb = F + (size_t)b * NTOK * FDIM;
    float* Pbase = Pout + ((size_t)b * NTOK + s * 64) * NTOK;

    float4 kreg[4];
    auto issue_load = [&](int mc) {
#pragma unroll
        for (int i = 0; i < 4; ++i) {
            int e = t + 256 * i;            // 0..1023 float4 slots
            int r = e >> 4, m4 = (e & 15) * 4;
            kreg[i] = *(const float4*)&Pbase[(size_t)r * NTOK + mc * 64 + m4];
        }
    };
    auto emit = [&](int mc, int bufi) {     // P = u*K*v -> global (in place) + LDS
#pragma unroll
        for (int i = 0; i < 4; ++i) {
            int e = t + 256 * i;
            int r = e >> 4, m4 = (e & 15) * 4;
            float ur = us[r];
            float4 p4;
            p4.x = kreg[i].x * ur * vs[mc * 64 + m4 + 0];
            p4.y = kreg[i].y * ur * vs[mc * 64 + m4 + 1];
            p4.z = kreg[i].z * ur * vs[mc * 64 + m4 + 2];
            p4.w = kreg[i].w * ur * vs[mc * 64 + m4 + 3];
            *(float4*)&Pbase[(size_t)r * NTOK + mc * 64 + m4] = p4;
            float* dst = &sP[bufi][r * 68 + m4];
            dst[0] = p4.x; dst[1] = p4.y; dst[2] = p4.z; dst[3] = p4.w;
        }
    };

    float acc[16][4] = {};

    issue_load(0);
    __syncthreads();          // vs/us visible
    emit(0, 0);
    __syncthreads();
    int cur = 0;

    for (int mc = 0; mc < 8; ++mc) {
        if (mc < 7) issue_load(mc + 1);     // next chunk's K in flight during GEMM

        // FT[64,256] += P_chunk[64,64] @ F[mchunk,256], float4 LDS reads
        const float* Fc = Fb + (size_t)(mc * 64) * FDIM + 4 * dg;
        const float* sp = sP[cur];
        for (int mm = 0; mm < 64; mm += 4) {
            float4 f0 = *(const float4*)&Fc[(size_t)(mm + 0) * FDIM];
            float4 f1 = *(const float4*)&Fc[(size_t)(mm + 1) * FDIM];
            float4 f2 = *(const float4*)&Fc[(size_t)(mm + 2) * FDIM];
            float4 f3 = *(const float4*)&Fc[(size_t)(mm + 3) * FDIM];
#pragma unroll
            for (int i = 0; i < 16; ++i) {
                float4 p = *(const float4*)&sp[(ng * 16 + i) * 68 + mm];
                acc[i][0] += p.x * f0.x + p.y * f1.x + p.z * f2.x + p.w * f3.x;
                acc[i][1] += p.x * f0.y + p.y * f1.y + p.z * f2.y + p.w * f3.y;
                acc[i][2] += p.x * f0.z + p.y * f1.z + p.z * f2.z + p.w * f3.z;
                acc[i][3] += p.x * f0.w + p.y * f1.w + p.z * f2.w + p.w * f3.w;
            }
        }

        if (mc < 7) {
            emit(mc + 1, cur ^ 1);
            __syncthreads();
            cur ^= 1;
        }
    }

#pragma unroll
    for (int i = 0; i < 16; ++i) {
        float4 o;
        o.x = acc[i][0]; o.y = acc[i][1]; o.z = acc[i][2]; o.w = acc[i][3];
        *(float4*)&FTout[((size_t)b * NTOK + s * 64 + ng * 16 + i) * FDIM + 4 * dg] = o;
    }
}

// =====================================================================
extern "C" void kernel_launch(void* const* d_in, const int* in_sizes, int n_in,
                              void* d_out, int out_size, void* d_ws, size_t ws_size,
                              hipStream_t stream) {
    const float* S      = (const float*)d_in[0];
    const float* F      = (const float*)d_in[1];
    const float* W_s    = (const float*)d_in[2];
    const float* b_s    = (const float*)d_in[3];
    const float* g_s    = (const float*)d_in[4];
    const float* beta_s = (const float*)d_in[5];
    const float* W_f    = (const float*)d_in[6];
    const float* b_f    = (const float*)d_in[7];
    const float* g_f    = (const float*)d_in[8];
    const float* beta_f = (const float*)d_in[9];

    float* wsf  = (float*)d_ws;
    float* WT_s = wsf;                        // 32768
    float* WT_f = wsf + 32768;                // 32768
    float* SP   = wsf + 65536;                // 65536*128
    float* FP   = SP + (size_t)65536 * 128;   // 65536*128
    float* U    = FP + (size_t)65536 * 128;   // 65536
    float* VFIN = U + 65536;                  // 65536 (final clipped v)

    float* Pout = (float*)d_out;                      // [128,512,512] (K32 then P, in place)
    float* FT   = Pout + (size_t)BSZ * NTOK * NTOK;   // [128,512,256]
    // fp16 K lives in the FT region during the sinkhorn phase:
    // 128*512*512*2 bytes == 128*512*256*4 bytes exactly.
    half_t* K16 = (half_t*)FT;

    transpose_w_kernel<<<128, 256, 0, stream>>>(W_s, WT_s);
    transpose_w_kernel<<<128, 256, 0, stream>>>(W_f, WT_f);

    proj_kernel<<<2048, 256, 0, stream>>>(S, WT_s, b_s, g_s, beta_s, SP);
    proj_kernel<<<2048, 256, 0, stream>>>(F, WT_f, b_f, g_f, beta_f, FP);

    cosk_kernel<<<dim3(64, 128), 256, 0, stream>>>(SP, FP, Pout, K16);

    // all 30 iterations in ONE dispatch; block b owns batch element b;
    // intra-block sync only.
    sinkhorn_fused_kernel<<<128, 1024, 0, stream>>>(K16, U, VFIN);

    final_kernel<<<1024, 256, 0, stream>>>(VFIN, U, F, Pout, FT);
}